// Round 2
// baseline (135.007 us; speedup 1.0000x reference)
//
#include <hip/hip_runtime.h>
#include <math.h>

#define C_IN  128
#define H_IN  56
#define W_IN  56
#define N_IN  8
#define O_MID 64
#define KK    5
#define NCLS  2

// ws layout (floats): Weff[5][128][12]  (slots 0..9 used = [dj][k], 10,11 pad)  -> 7680
//                     beff[2] at offset 7680
#define WEFF_STRIDE 12
#define WEFF_SIZE   (5 * C_IN * WEFF_STRIDE)

__global__ __launch_bounds__(256) void k_weff(const float* __restrict__ Wt,
                                              const float* __restrict__ bias,
                                              const float* __restrict__ Wlin,
                                              const float* __restrict__ blin,
                                              float* __restrict__ ws) {
    const int p  = blockIdx.x;      // 0..24
    const int t  = threadIdx.x;     // 0..255
    const int c  = t >> 1;
    const int k  = t & 1;
    const int di = p / KK;
    const int dj = p - di * KK;
    float s = 0.f;
#pragma unroll 8
    for (int o = 0; o < O_MID; ++o)
        s += Wlin[k * O_MID + o] * Wt[(o * C_IN + c) * (KK * KK) + p];
    ws[(di * C_IN + c) * WEFF_STRIDE + dj * 2 + k] = s;
    if (p == 0 && t < 2) {
        float b = blin[t];
        for (int o = 0; o < O_MID; ++o) b += Wlin[t * O_MID + o] * bias[o];
        ws[WEFF_SIZE + t] = b;
    }
}

// Tile: 8x8 output pixels per block. Halo: 12x12 per channel.
// Block: 320 threads = 5 waves; wave = di (kernel row).
// Lane: strip = lane&15 (16 strips: sy=strip>>1 in 0..7, sx0=(strip&1)*4),
//       cq = lane>>4 (4 channel-quarters, interleaved c = cq + 4*i).
// Channels staged in 4 LDS chunks of 32 (4*32 = 128 = C_IN exactly).
#define CHUNK_C 32
#define N_CHUNK 4

__global__ __launch_bounds__(320) void k_main(const float* __restrict__ x,
                                              const float* __restrict__ ws,
                                              float* __restrict__ out) {
    __shared__ float xs[CHUNK_C * 144];      // [c][12][12]  18432 B
    __shared__ float wsh[WEFF_SIZE];         // 30720 B
    float* red = xs;                         // aliased: [5][64][2][4] = 2560 floats

    const int tid   = threadIdx.x;
    const int di    = tid >> 6;              // wave id = kernel row 0..4
    const int lane  = tid & 63;
    const int strip = lane & 15;
    const int cq    = lane >> 4;
    const int sy    = strip >> 1;
    const int sx0   = (strip & 1) << 2;
    const int x0g   = blockIdx.x * 8;
    const int y0g   = blockIdx.y * 8;
    const int n     = blockIdx.z;

    // stage Weff into LDS
    for (int i = tid; i < WEFF_SIZE; i += 320) wsh[i] = ws[i];
    const float b0 = ws[WEFF_SIZE + 0];
    const float b1 = ws[WEFF_SIZE + 1];

    const float* xn = x + (size_t)n * (C_IN * H_IN * W_IN);

    float acc[5][2][4];                      // [dj][k][j]
#pragma unroll
    for (int a = 0; a < 5; ++a)
#pragma unroll
        for (int b = 0; b < 2; ++b)
#pragma unroll
            for (int j = 0; j < 4; ++j) acc[a][b][j] = 0.f;

    const int ry = sy + di;                  // halo row this lane reads

    for (int cc = 0; cc < N_CHUNK; ++cc) {
        __syncthreads();                     // protect xs from previous readers
        // load 32 channels' 12x12 halo, zero-filled at borders
        for (int i = tid; i < CHUNK_C * 144; i += 320) {
            const int c  = i / 144;
            const int r  = i - c * 144;
            const int ly = r / 12;
            const int lx = r - ly * 12;
            const int gy = y0g + ly - 2;
            const int gx = x0g + lx - 2;
            float v = 0.f;
            if ((unsigned)gy < H_IN && (unsigned)gx < W_IN)
                v = xn[(size_t)(cc * CHUNK_C + c) * (H_IN * W_IN) + gy * W_IN + gx];
            xs[i] = v;
        }
        __syncthreads();

#pragma unroll
        for (int i = 0; i < CHUNK_C / 4; ++i) {
            const int cl = cq + (i << 2);            // 0..31 within chunk
            const int cg = cc * CHUNK_C + cl;        // global channel 0..127
            const float4 xa = *(const float4*)&xs[cl * 144 + ry * 12 + sx0];
            const float4 xb = *(const float4*)&xs[cl * 144 + ry * 12 + sx0 + 4];
            const float xr[8] = {xa.x, xa.y, xa.z, xa.w, xb.x, xb.y, xb.z, xb.w};
            const float* wp = &wsh[(di * C_IN + cg) * WEFF_STRIDE];
            const float4 wa = *(const float4*)(wp);
            const float4 wb = *(const float4*)(wp + 4);
            const float2 wc = *(const float2*)(wp + 8);
            const float wv[10] = {wa.x, wa.y, wa.z, wa.w,
                                  wb.x, wb.y, wb.z, wb.w, wc.x, wc.y};
#pragma unroll
            for (int dj = 0; dj < 5; ++dj)
#pragma unroll
                for (int j = 0; j < 4; ++j) {
                    const float xv = xr[dj + j];
                    acc[dj][0][j] = fmaf(xv, wv[dj * 2 + 0], acc[dj][0][j]);
                    acc[dj][1][j] = fmaf(xv, wv[dj * 2 + 1], acc[dj][1][j]);
                }
        }
    }

    // reduce across the 4 channel-quarters (lane bits 4,5)
#pragma unroll
    for (int a = 0; a < 5; ++a)
#pragma unroll
        for (int b = 0; b < 2; ++b)
#pragma unroll
            for (int j = 0; j < 4; ++j) {
                float v = acc[a][b][j];
                v += __shfl_xor(v, 16, 64);
                v += __shfl_xor(v, 32, 64);
                acc[a][b][j] = v;
            }

    __syncthreads();                         // all xs reads done; xs becomes 'red'

    if (cq == 0) {
#pragma unroll
        for (int j = 0; j < 4; ++j) {
            const int pix = sy * 8 + sx0 + j;
#pragma unroll
            for (int k = 0; k < 2; ++k) {
                const float be = k ? b1 : b0;
                float A = 0.f, X = 0.f, Cs = 0.f;
#pragma unroll
                for (int dj = 0; dj < 5; ++dj) {
                    const float v  = acc[dj][k][j] + be;
                    const float av = fabsf(v);
                    A  += av;
                    X  += av * (float)(dj - 2);
                    Cs += v;
                }
                float* rp = &red[((di * 64 + pix) * 2 + k) * 4];
                rp[0] = A;
                rp[1] = X;
                rp[2] = Cs;
                rp[3] = A * (float)(di - 2);
            }
        }
    }
    __syncthreads();

    if (tid < 128) {
        const int pix = tid >> 1;
        const int k   = tid & 1;
        float A = 0.f, X = 0.f, Cs = 0.f, Y = 0.f;
#pragma unroll
        for (int d = 0; d < 5; ++d) {
            const float* rp = &red[((d * 64 + pix) * 2 + k) * 4];
            A += rp[0]; X += rp[1]; Cs += rp[2]; Y += rp[3];
        }
        const float xd = X / A;
        const float yd = Y / A;
        const float drift = sqrtf(xd * xd + yd * yd);
        const float o = Cs * expf(-0.5f * drift);
        const int gy = y0g + (pix >> 3);
        const int gx = x0g + (pix & 7);
        out[((size_t)(n * H_IN + gy) * W_IN + gx) * NCLS + k] = o;
    }
}

extern "C" void kernel_launch(void* const* d_in, const int* in_sizes, int n_in,
                              void* d_out, int out_size, void* d_ws, size_t ws_size,
                              hipStream_t stream) {
    const float* x    = (const float*)d_in[0];
    const float* Wt   = (const float*)d_in[1];
    const float* bias = (const float*)d_in[2];
    const float* Wlin = (const float*)d_in[3];
    const float* blin = (const float*)d_in[4];
    float* ws = (float*)d_ws;

    k_weff<<<dim3(KK * KK), dim3(256), 0, stream>>>(Wt, bias, Wlin, blin, ws);
    k_main<<<dim3(7, 7, N_IN), dim3(320), 0, stream>>>(x, ws, (float*)d_out);
}

// Round 3
// 103.058 us; speedup vs baseline: 1.3100x; 1.3100x over previous
//
#include <hip/hip_runtime.h>
#include <math.h>

#define C_IN  128
#define H_IN  56
#define W_IN  56
#define N_IN  8
#define O_MID 64
#define KK    5
#define NCLS  2

// ws layout (floats): Weff[5][128][12] (slots 0..9 = [dj][k], 10,11 pad) -> 7680
//                     beff[2] at offset 7680
#define WEFF_STRIDE 12
#define WEFF_SIZE   (5 * C_IN * WEFF_STRIDE)

// 50 blocks: b = p*2 + k. 256 threads: c = t&127, o-half = t>>7.
__global__ __launch_bounds__(256) void k_weff(const float* __restrict__ Wt,
                                              const float* __restrict__ bias,
                                              const float* __restrict__ Wlin,
                                              const float* __restrict__ blin,
                                              float* __restrict__ ws) {
    const int b = blockIdx.x;
    const int p = b >> 1;
    const int k = b & 1;
    const int t = threadIdx.x;
    const int c = t & 127;
    const int oh = t >> 7;
    float s = 0.f;
#pragma unroll
    for (int oo = 0; oo < 32; ++oo) {
        const int o = oh * 32 + oo;
        s += Wlin[k * O_MID + o] * Wt[(o * C_IN + c) * (KK * KK) + p];
    }
    __shared__ float part[256];
    part[t] = s;
    __syncthreads();
    if (t < 128) {
        const int di = p / KK;
        const int dj = p - di * KK;
        ws[(di * C_IN + c) * WEFF_STRIDE + dj * 2 + k] = part[c] + part[c + 128];
    }
    if (p == 0 && t < 64) {
        float v = Wlin[k * O_MID + t] * bias[t];
#pragma unroll
        for (int off = 32; off; off >>= 1) v += __shfl_down(v, off, 64);
        if (t == 0) ws[WEFF_SIZE + k] = v + blin[k];
    }
}

// Tile: 8x8 output pixels/block; halo 12x12/channel; 320 thr = 5 waves (wave=di).
// Lane: strip = lane&15 (sy=strip>>1, sx0=(strip&1)*4), cq = lane>>4.
// Channels: 8 chunks of 16, double-buffered LDS with register prefetch.
#define CHUNK_C  16
#define N_CHUNK  8
#define CH_PAD   148                     // padded channel stride (floats)
#define CHUNK_EL (CHUNK_C * 144)         // 2304 payload elements per chunk

__global__ __launch_bounds__(320) void k_main(const float* __restrict__ x,
                                              const float* __restrict__ ws,
                                              float* __restrict__ out) {
    __shared__ float xs[2][CHUNK_C * CH_PAD];   // 2 x 9472 B
    __shared__ float wsh[WEFF_SIZE];            // 30720 B
    float* red = &xs[0][0];                     // aliased: [5][64][2][4] = 2560 floats

    const int tid   = threadIdx.x;
    const int di    = tid >> 6;
    const int lane  = tid & 63;
    const int strip = lane & 15;
    const int cq    = lane >> 4;
    const int sy    = strip >> 1;
    const int sx0   = (strip & 1) << 2;
    const int x0g   = blockIdx.x * 8;
    const int y0g   = blockIdx.y * 8;
    const int n     = blockIdx.z;

    // stage Weff into LDS (pipelines with chunk-0 prefetch below)
    for (int i = tid; i < WEFF_SIZE; i += 320) wsh[i] = ws[i];
    const float b0 = ws[WEFF_SIZE + 0];
    const float b1 = ws[WEFF_SIZE + 1];

    const float* xn = x + (size_t)n * (C_IN * H_IN * W_IN);

    // precompute per-thread staging addresses (8 elements/thread/chunk)
    int goff[8];   // global offset within chunk-0 channel range, -1 = load 0
    int widx[8];   // padded LDS write index, -1 = skip
#pragma unroll
    for (int j = 0; j < 8; ++j) {
        const int i = tid + 320 * j;
        if (i < CHUNK_EL) {
            const int c  = i / 144;
            const int r  = i - c * 144;
            const int ly = r / 12;
            const int lx = r - ly * 12;
            const int gy = y0g + ly - 2;
            const int gx = x0g + lx - 2;
            widx[j] = i + 4 * c;   // c*148 + r
            goff[j] = ((unsigned)gy < H_IN && (unsigned)gx < W_IN)
                          ? (c * (H_IN * W_IN) + gy * W_IN + gx) : -1;
        } else { widx[j] = -1; goff[j] = -1; }
    }

    // stage chunk 0
    {
        float pf[8];
#pragma unroll
        for (int j = 0; j < 8; ++j)
            pf[j] = (goff[j] >= 0) ? xn[goff[j]] : 0.f;
#pragma unroll
        for (int j = 0; j < 8; ++j)
            if (widx[j] >= 0) xs[0][widx[j]] = pf[j];
    }
    __syncthreads();

    float acc[5][2][4];
#pragma unroll
    for (int a = 0; a < 5; ++a)
#pragma unroll
        for (int b = 0; b < 2; ++b)
#pragma unroll
            for (int j = 0; j < 4; ++j) acc[a][b][j] = 0.f;

    const int ry = sy + di;
    const int rbase = ry * 12 + sx0;

    for (int cc = 0; cc < N_CHUNK; ++cc) {
        float* cur = xs[cc & 1];
        float* nxt = xs[(cc & 1) ^ 1];
        float pf[8];
        if (cc < N_CHUNK - 1) {
            const int cofs = (cc + 1) * CHUNK_C * (H_IN * W_IN);
#pragma unroll
            for (int j = 0; j < 8; ++j)
                pf[j] = (goff[j] >= 0) ? xn[cofs + goff[j]] : 0.f;
        }
#pragma unroll
        for (int i = 0; i < CHUNK_C / 4; ++i) {
            const int cl = cq + (i << 2);
            const int cg = cc * CHUNK_C + cl;
            const float4 xa = *(const float4*)&cur[cl * CH_PAD + rbase];
            const float4 xb = *(const float4*)&cur[cl * CH_PAD + rbase + 4];
            const float xr[8] = {xa.x, xa.y, xa.z, xa.w, xb.x, xb.y, xb.z, xb.w};
            const float* wp = &wsh[(di * C_IN + cg) * WEFF_STRIDE];
            const float4 wa = *(const float4*)(wp);
            const float4 wb = *(const float4*)(wp + 4);
            const float2 wc = *(const float2*)(wp + 8);
            const float wv[10] = {wa.x, wa.y, wa.z, wa.w,
                                  wb.x, wb.y, wb.z, wb.w, wc.x, wc.y};
#pragma unroll
            for (int dj = 0; dj < 5; ++dj)
#pragma unroll
                for (int j = 0; j < 4; ++j) {
                    const float xv = xr[dj + j];
                    acc[dj][0][j] = fmaf(xv, wv[dj * 2 + 0], acc[dj][0][j]);
                    acc[dj][1][j] = fmaf(xv, wv[dj * 2 + 1], acc[dj][1][j]);
                }
        }
        if (cc < N_CHUNK - 1) {
#pragma unroll
            for (int j = 0; j < 8; ++j)
                if (widx[j] >= 0) nxt[widx[j]] = pf[j];
        }
        __syncthreads();
    }

    // reduce across channel-quarters (lane bits 4,5)
#pragma unroll
    for (int a = 0; a < 5; ++a)
#pragma unroll
        for (int b = 0; b < 2; ++b)
#pragma unroll
            for (int j = 0; j < 4; ++j) {
                float v = acc[a][b][j];
                v += __shfl_xor(v, 16, 64);
                v += __shfl_xor(v, 32, 64);
                acc[a][b][j] = v;
            }
    // loop-exit barrier already passed; xs free for 'red'
    if (cq == 0) {
#pragma unroll
        for (int j = 0; j < 4; ++j) {
            const int pix = sy * 8 + sx0 + j;
#pragma unroll
            for (int k = 0; k < 2; ++k) {
                const float be = k ? b1 : b0;
                float A = 0.f, X = 0.f, Cs = 0.f;
#pragma unroll
                for (int dj = 0; dj < 5; ++dj) {
                    const float v  = acc[dj][k][j] + be;
                    const float av = fabsf(v);
                    A  += av;
                    X  += av * (float)(dj - 2);
                    Cs += v;
                }
                float* rp = &red[((di * 64 + pix) * 2 + k) * 4];
                rp[0] = A;
                rp[1] = X;
                rp[2] = Cs;
                rp[3] = A * (float)(di - 2);
            }
        }
    }
    __syncthreads();

    if (tid < 128) {
        const int pix = tid >> 1;
        const int k   = tid & 1;
        float A = 0.f, X = 0.f, Cs = 0.f, Y = 0.f;
#pragma unroll
        for (int d = 0; d < 5; ++d) {
            const float* rp = &red[((d * 64 + pix) * 2 + k) * 4];
            A += rp[0]; X += rp[1]; Cs += rp[2]; Y += rp[3];
        }
        const float xd = X / A;
        const float yd = Y / A;
        const float drift = sqrtf(xd * xd + yd * yd);
        const float o = Cs * expf(-0.5f * drift);
        const int gy = y0g + (pix >> 3);
        const int gx = x0g + (pix & 7);
        out[((size_t)(n * H_IN + gy) * W_IN + gx) * NCLS + k] = o;
    }
}

extern "C" void kernel_launch(void* const* d_in, const int* in_sizes, int n_in,
                              void* d_out, int out_size, void* d_ws, size_t ws_size,
                              hipStream_t stream) {
    const float* x    = (const float*)d_in[0];
    const float* Wt   = (const float*)d_in[1];
    const float* bias = (const float*)d_in[2];
    const float* Wlin = (const float*)d_in[3];
    const float* blin = (const float*)d_in[4];
    float* ws = (float*)d_ws;

    k_weff<<<dim3(KK * KK * NCLS), dim3(256), 0, stream>>>(Wt, bias, Wlin, blin, ws);
    k_main<<<dim3(7, 7, N_IN), dim3(320), 0, stream>>>(x, ws, (float*)d_out);
}